// Round 4
// baseline (288.525 us; speedup 1.0000x reference)
//
#include <hip/hip_runtime.h>
#include <hip/hip_bf16.h>

typedef __bf16 bf16;
typedef __attribute__((ext_vector_type(8))) __bf16 bf16x8;
typedef __attribute__((ext_vector_type(4))) __bf16 bf16x4;
typedef __attribute__((ext_vector_type(2))) __bf16 bf16x2;
typedef __attribute__((ext_vector_type(4))) float f32x4;

#define MFMA16(a, b, c) __builtin_amdgcn_mfma_f32_16x16x32_bf16((a), (b), (c), 0, 0, 0)

constexpr int Bn = 2, Tn = 2048, Cn = 1024, Hn = 16, Dn = 64;
constexpr int Mn = Bn * Tn;
constexpr int WSZ = Cn * Cn;
constexpr int XSZ = Mn * Cn;
constexpr int BH = Bn * Hn;            // 32
constexpr int NSPLIT = 2;              // kv-split factor
constexpr int ROWS = BH * Tn;          // 65536 (bh,q) rows
constexpr float LOG2E = 1.44269504088896f;

// async global->LDS, 16B/lane: LDS dest = wave-uniform base + lane*16
__device__ __forceinline__ void async_cp16(bf16* lds, const bf16* g) {
  __builtin_amdgcn_global_load_lds(
      (const __attribute__((address_space(1))) unsigned int*)g,
      (__attribute__((address_space(3))) unsigned int*)lds, 16, 0, 0);
}

struct GemmArgs {
  const bf16* A[3];
  const bf16* Bt[3];
  const float* bias[3];
  void* out[3];
  float scale[3];
  int layout[3];   // 0 = fp32 [M,N]; 1 = bf16 [B,H,T,D]; 2 = bf16 [B,H,D,T] (transposed)
};

struct TransArgs {
  const float* W[4];
  bf16* Wt[4];
};

struct ConvArgs {
  const float* src[3];
};

// ---------------- fp32 -> bf16 bulk convert (query/key/value) ----------------
__global__ __launch_bounds__(256) void convert_bf16(ConvArgs ca, bf16* __restrict__ dst) {
  const int z = blockIdx.y;
  const float* __restrict__ s = ca.src[z];
  size_t idx = ((size_t)blockIdx.x * 256 + threadIdx.x) * 8;
  float4 a = *(const float4*)&s[idx];
  float4 b = *(const float4*)&s[idx + 4];
  bf16x8 o = {(bf16)a.x, (bf16)a.y, (bf16)a.z, (bf16)a.w,
              (bf16)b.x, (bf16)b.y, (bf16)b.z, (bf16)b.w};
  *(bf16x8*)&dst[(size_t)z * XSZ + idx] = o;
}

// ---------------- W[k][n] fp32 -> Wt[n][k] bf16 (4 weights via grid.z) ----------------
__global__ __launch_bounds__(256) void transpose_convert(TransArgs ta) {
  const float* __restrict__ W = ta.W[blockIdx.z];
  bf16* __restrict__ Wt = ta.Wt[blockIdx.z];
  __shared__ float tile[32][33];
  const int tx = threadIdx.x, ty = threadIdx.y;  // (32,8)
  const int x = blockIdx.x * 32 + tx;
  const int y0 = blockIdx.y * 32;
  for (int j = 0; j < 32; j += 8) tile[ty + j][tx] = W[(y0 + ty + j) * Cn + x];
  __syncthreads();
  const int n0 = blockIdx.x * 32;
  const int k = blockIdx.y * 32 + tx;
  for (int j = 0; j < 32; j += 8)
    Wt[(n0 + ty + j) * Cn + k] = (bf16)tile[tx][ty + j];
}

// ---------------- GEMM: C[M,N] = A[M,K] @ Wt[N,K]^T + bias ----------------
// 128x128 tile, BK=64, async 16B staging, XOR chunk swizzle -> conflict-free b128 reads.
__global__ __launch_bounds__(256) void gemm_kernel(GemmArgs args, int K) {
  const int z = blockIdx.z;
  const bf16* __restrict__ A = args.A[z];
  const bf16* __restrict__ Bt = args.Bt[z];
  const float* __restrict__ bias = args.bias[z];
  const float scale = args.scale[z];
  const int layout = args.layout[z];

  __shared__ bf16 As[128 * 64];
  __shared__ bf16 Bs[128 * 64];

  const int tid = threadIdx.x;
  const int w = tid >> 6, lane = tid & 63;
  const int wm = w >> 1, wn = w & 1;
  const int g = lane >> 4, l15 = lane & 15;
  const int r8 = lane >> 3, c8 = lane & 7;
  const int soff = (c8 ^ r8) << 3;
  const int kk = l15 & 7;
  const int off0 = (g ^ kk) << 3;
  const int off1 = ((4 + g) ^ kk) << 3;
  const int m0 = blockIdx.y * 128, n0 = blockIdx.x * 128;

  f32x4 acc[4][4] = {};

  for (int k0 = 0; k0 < K; k0 += 64) {
    __syncthreads();
    for (int i = 0; i < 4; i++) {
      int p = w * 4 + i;
      async_cp16(&As[p * 512], &A[(size_t)(m0 + p * 8 + r8) * K + k0 + soff]);
    }
    for (int i = 0; i < 4; i++) {
      int p = w * 4 + i;
      async_cp16(&Bs[p * 512], &Bt[(size_t)(n0 + p * 8 + r8) * K + k0 + soff]);
    }
    __syncthreads();

    for (int ks = 0; ks < 2; ks++) {
      const int off = ks ? off1 : off0;
      bf16x8 af[4], bfr[4];
      for (int mt = 0; mt < 4; mt++)
        af[mt] = *(const bf16x8*)&As[(wm * 64 + mt * 16 + l15) * 64 + off];
      for (int nt = 0; nt < 4; nt++)
        bfr[nt] = *(const bf16x8*)&Bs[(wn * 64 + nt * 16 + l15) * 64 + off];
      for (int mt = 0; mt < 4; mt++)
        for (int nt = 0; nt < 4; nt++)
          acc[mt][nt] = MFMA16(af[mt], bfr[nt], acc[mt][nt]);
    }
  }

  // epilogue: C/D layout row=(lane>>4)*4+r, col=lane&15
  for (int mt = 0; mt < 4; mt++) {
    for (int nt = 0; nt < 4; nt++) {
      int gn = n0 + wn * 64 + nt * 16 + l15;
      float bb = bias[gn];
      int gm0 = m0 + wm * 64 + mt * 16 + g * 4;
      float v[4];
      for (int r = 0; r < 4; r++) v[r] = (acc[mt][nt][r] + bb) * scale;
      if (layout == 2) {
        // V^T: bf16 [B,H,D,T]; r -> consecutive t
        int b = gm0 >> 11, t = gm0 & 2047, h = gn >> 6, d = gn & 63;
        bf16x4 ov = {(bf16)v[0], (bf16)v[1], (bf16)v[2], (bf16)v[3]};
        *(bf16x4*)&((bf16*)args.out[z])[(size_t)((b * Hn + h) * Dn + d) * Tn + t] = ov;
      } else if (layout == 1) {
        int b = gm0 >> 11, t = gm0 & 2047, h = gn >> 6, d = gn & 63;
        bf16* o = (bf16*)args.out[z] + (size_t)((b * Hn + h) * Tn + t) * Dn + d;
        for (int r = 0; r < 4; r++) o[(size_t)r * Dn] = (bf16)v[r];
      } else {
        float* o = (float*)args.out[z] + (size_t)gm0 * Cn + gn;
        for (int r = 0; r < 4; r++) o[(size_t)r * Cn] = v[r];
      }
    }
  }
}

// ---------------- Flash attention v4: kv-split, S^T = K Q^T, O^T = V^T P^T ----------------
// Grid 1024 = NSPLIT(2) x qblk(16) x bh(32); bh in low 5 bits -> XCD L2 locality.
// Each block: 128 q rows, 16 KV tiles of 64. Emits unnormalized O^T + (m,l) partials.
constexpr int LDP = 72;

__global__ __launch_bounds__(256) void attn_kernel(const bf16* __restrict__ Qh,
                                                   const bf16* __restrict__ Kh,
                                                   const bf16* __restrict__ VhT,
                                                   float* __restrict__ Opart,
                                                   float2* __restrict__ ML) {
  __shared__ bf16 Ks[64 * 64];    // [kv][d], chunk-swizzled
  __shared__ bf16 Vt[64 * 64];    // [d][kv], chunk-swizzled
  __shared__ bf16 Pt[128 * LDP];  // [q][kv], wave-private rows

  const int tid = threadIdx.x;
  const int w = tid >> 6, lane = tid & 63;
  const int g = lane >> 4, l15 = lane & 15;
  const int id = blockIdx.x;
  const int bh = id & 31;
  const int q0 = ((id >> 5) & 15) * 128;
  const int split = id >> 9;
  const size_t hb = (size_t)bh * Tn * Dn;   // Q/K base ([B,H,T,D])
  const size_t hbT = (size_t)bh * Dn * Tn;  // V^T base ([B,H,D,T])
  const int r8 = lane >> 3, c8 = lane & 7;
  const int soff = (c8 ^ r8) << 3;
  const int kk = l15 & 7;
  const int off0 = (g ^ kk) << 3;
  const int off1 = ((4 + g) ^ kk) << 3;

  // Q fragments from global (B-operand of S^T)
  bf16x8 qf[2][2];
  for (int qt = 0; qt < 2; qt++) {
    const bf16* qp = Qh + hb + (size_t)(q0 + w * 32 + qt * 16 + l15) * Dn;
    qf[qt][0] = *(const bf16x8*)(qp + g * 8);
    qf[qt][1] = *(const bf16x8*)(qp + 32 + g * 8);
  }

  f32x4 o[2][4] = {};
  float m_run[2] = {-1e30f, -1e30f}, l_run[2] = {0.f, 0.f};

  const int kt0 = split * (Tn / 64 / NSPLIT);
  const int kt1 = kt0 + Tn / 64 / NSPLIT;
  for (int kt = kt0; kt < kt1; kt++) {
    const int t0 = kt * 64;
    __syncthreads();
    // K tile [kv][d] async, swizzled source columns
    for (int i = 0; i < 2; i++) {
      int p = w * 2 + i;
      async_cp16(&Ks[p * 512], &Kh[hb + (size_t)(t0 + p * 8 + r8) * Dn + soff]);
    }
    // V^T tile [d][kv] async (precomputed transpose), swizzled source columns
    for (int i = 0; i < 2; i++) {
      int p = w * 2 + i;
      async_cp16(&Vt[p * 512], &VhT[hbT + (size_t)(p * 8 + r8) * Tn + t0 + soff]);
    }
    __syncthreads();

    // S^T[kv][q]: A = K-frag (shared across q-tiles), B = Q-frag
    f32x4 s[2][4] = {};
    for (int nt = 0; nt < 4; nt++) {
      const bf16* kp = &Ks[(nt * 16 + l15) * 64];
      bf16x8 kf0 = *(const bf16x8*)(kp + off0);
      bf16x8 kf1 = *(const bf16x8*)(kp + off1);
      for (int qt = 0; qt < 2; qt++) {
        s[qt][nt] = MFMA16(kf0, qf[qt][0], s[qt][nt]);
        s[qt][nt] = MFMA16(kf1, qf[qt][1], s[qt][nt]);
      }
    }

    // online softmax over kv (regs + g-groups)
    for (int qt = 0; qt < 2; qt++) {
      float mx = s[qt][0][0];
      for (int nt = 0; nt < 4; nt++)
        for (int r = 0; r < 4; r++) mx = fmaxf(mx, s[qt][nt][r]);
      mx = fmaxf(mx, __shfl_xor(mx, 16));
      mx = fmaxf(mx, __shfl_xor(mx, 32));
      float mn = fmaxf(m_run[qt], mx);
      float alpha = exp2f(m_run[qt] - mn);
      float rs = 0.f;
      for (int nt = 0; nt < 4; nt++)
        for (int r = 0; r < 4; r++) {
          float pe = exp2f(s[qt][nt][r] - mn);
          s[qt][nt][r] = pe;
          rs += pe;
        }
      rs += __shfl_xor(rs, 16);
      rs += __shfl_xor(rs, 32);
      l_run[qt] = l_run[qt] * alpha + rs;
      m_run[qt] = mn;
      for (int dt = 0; dt < 4; dt++) o[qt][dt] = o[qt][dt] * alpha;

      bf16* prow = &Pt[(size_t)(w * 32 + qt * 16 + l15) * LDP];
      for (int nt = 0; nt < 4; nt++) {
        bf16x2 p0 = {(bf16)s[qt][nt][0], (bf16)s[qt][nt][1]};
        bf16x2 p1 = {(bf16)s[qt][nt][2], (bf16)s[qt][nt][3]};
        *(bf16x2*)&prow[nt * 16 + g * 4] = p0;
        *(bf16x2*)&prow[nt * 16 + g * 4 + 2] = p1;
      }
    }

    // O^T += V^T P^T
    for (int ks = 0; ks < 2; ks++) {
      const int offk = ks ? off1 : off0;
      bf16x8 vf[4];
      for (int dt = 0; dt < 4; dt++)
        vf[dt] = *(const bf16x8*)&Vt[(dt * 16 + l15) * 64 + offk];
      for (int qt = 0; qt < 2; qt++) {
        bf16x8 pf = *(const bf16x8*)&Pt[(size_t)(w * 32 + qt * 16 + l15) * LDP + ks * 32 + g * 8];
        for (int dt = 0; dt < 4; dt++)
          o[qt][dt] = MFMA16(vf[dt], pf, o[qt][dt]);
      }
    }
  }

  // epilogue: unnormalized O^T partials + (m,l); lane owns q rows qt*16+l15, d = dt*16+g*4+r
  for (int qt = 0; qt < 2; qt++) {
    int qrow = q0 + w * 32 + qt * 16 + l15;
    size_t row = (size_t)(split * BH + bh) * Tn + qrow;
    float* orow = Opart + row * 64;
    for (int dt = 0; dt < 4; dt++)
      *(f32x4*)&orow[dt * 16 + g * 4] = o[qt][dt];
    if (g == 0) ML[row] = make_float2(m_run[qt], l_run[qt]);
  }
}

// ---------------- merge the NSPLIT partials -> AO bf16 [B,T,C] ----------------
__global__ __launch_bounds__(256) void merge_kernel(const float* __restrict__ Opart,
                                                    const float2* __restrict__ ML,
                                                    bf16* __restrict__ AO) {
  int idx = blockIdx.x * 256 + threadIdx.x;   // 8 elements per thread
  int row = idx >> 3, dc = (idx & 7) * 8;
  float2 ml0 = ML[row];
  float2 ml1 = ML[(size_t)BH * Tn + row];
  float m = fmaxf(ml0.x, ml1.x);
  float a0 = exp2f(ml0.x - m), a1 = exp2f(ml1.x - m);
  float inv = 1.0f / (a0 * ml0.y + a1 * ml1.y);
  float s0 = a0 * inv, s1 = a1 * inv;
  const float* p0 = Opart + (size_t)row * 64 + dc;
  const float* p1 = p0 + (size_t)BH * Tn * 64;
  f32x4 x0 = *(const f32x4*)p0, x1 = *(const f32x4*)(p0 + 4);
  f32x4 y0 = *(const f32x4*)p1, y1 = *(const f32x4*)(p1 + 4);
  f32x4 r0 = x0 * s0 + y0 * s1;
  f32x4 r1 = x1 * s0 + y1 * s1;
  int bh = row >> 11, q = row & 2047;
  int b = bh >> 4, h = bh & 15;
  bf16x8 ov = {(bf16)r0[0], (bf16)r0[1], (bf16)r0[2], (bf16)r0[3],
               (bf16)r1[0], (bf16)r1[1], (bf16)r1[2], (bf16)r1[3]};
  *(bf16x8*)&AO[(size_t)(b * Tn + q) * Cn + h * Dn + dc] = ov;
}

extern "C" void kernel_launch(void* const* d_in, const int* in_sizes, int n_in,
                              void* d_out, int out_size, void* d_ws, size_t ws_size,
                              hipStream_t stream) {
  const float* query = (const float*)d_in[0];
  const float* key   = (const float*)d_in[1];
  const float* value = (const float*)d_in[2];
  const float* Wq = (const float*)d_in[3];
  const float* bq = (const float*)d_in[4];
  const float* Wk = (const float*)d_in[5];
  const float* bk = (const float*)d_in[6];
  const float* Wv = (const float*)d_in[7];
  const float* bv = (const float*)d_in[8];
  const float* Wo = (const float*)d_in[9];
  const float* bo = (const float*)d_in[10];

  bf16* p = (bf16*)d_ws;
  bf16* WqT = p; p += WSZ;
  bf16* WkT = p; p += WSZ;
  bf16* WvT = p; p += WSZ;
  bf16* WoT = p; p += WSZ;
  bf16* Xbf = p; p += 3 * XSZ;   // bf16 activations; reused as AO after QKV GEMM
  bf16* Qh = p; p += XSZ;
  bf16* Kh = p; p += XSZ;
  bf16* VhT = p; p += XSZ;
  bf16* AO = Xbf;
  float* Opart = (float*)p;      // NSPLIT * BH * Tn * 64 fp32 = 33.5 MB
  float2* ML = (float2*)(Opart + (size_t)NSPLIT * BH * Tn * 64);  // 1 MB

  TransArgs ta;
  ta.W[0] = Wq; ta.W[1] = Wk; ta.W[2] = Wv; ta.W[3] = Wo;
  ta.Wt[0] = WqT; ta.Wt[1] = WkT; ta.Wt[2] = WvT; ta.Wt[3] = WoT;
  transpose_convert<<<dim3(32, 32, 4), dim3(32, 8), 0, stream>>>(ta);

  ConvArgs ca;
  ca.src[0] = query; ca.src[1] = key; ca.src[2] = value;
  convert_bf16<<<dim3(XSZ / 2048, 3), 256, 0, stream>>>(ca, Xbf);

  GemmArgs ga;
  ga.A[0] = Xbf; ga.A[1] = Xbf + XSZ; ga.A[2] = Xbf + 2 * XSZ;
  ga.Bt[0] = WqT;  ga.Bt[1] = WkT; ga.Bt[2] = WvT;
  ga.bias[0] = bq; ga.bias[1] = bk; ga.bias[2] = bv;
  ga.out[0] = Qh;  ga.out[1] = Kh;  ga.out[2] = VhT;
  ga.scale[0] = 0.125f * LOG2E; ga.scale[1] = 1.0f; ga.scale[2] = 1.0f;
  ga.layout[0] = 1; ga.layout[1] = 1; ga.layout[2] = 2;
  gemm_kernel<<<dim3(Cn / 128, Mn / 128, 3), 256, 0, stream>>>(ga, Cn);

  attn_kernel<<<dim3(NSPLIT * 512), 256, 0, stream>>>(Qh, Kh, VhT, Opart, ML);
  merge_kernel<<<dim3(ROWS * 8 / 256), 256, 0, stream>>>(Opart, ML, AO);

  GemmArgs gb;
  gb.A[0] = AO; gb.Bt[0] = WoT; gb.bias[0] = bo; gb.out[0] = d_out; gb.scale[0] = 1.0f;
  gb.layout[0] = 0;
  gb.A[1] = gb.A[2] = nullptr; gb.Bt[1] = gb.Bt[2] = nullptr;
  gb.bias[1] = gb.bias[2] = nullptr; gb.out[1] = gb.out[2] = nullptr;
  gb.scale[1] = gb.scale[2] = 1.0f; gb.layout[1] = gb.layout[2] = 0;
  gemm_kernel<<<dim3(Cn / 128, Mn / 128, 1), 256, 0, stream>>>(gb, Cn);
}